// Round 5
// baseline (758.570 us; speedup 1.0000x reference)
//
#include <hip/hip_runtime.h>
#include <hip/hip_bf16.h>
#include <utility>

// fUpModule CG tensor product, MAXL=5, TAUS=OUT_TAUS=8, BATCH=1024, fp32 I/O.
// R5: single kernel; 512-thread blocks (8 waves -> 32 waves/CU with 36KB LDS);
// stage-1 work split into cost-balanced (slot, m-range) items over 8 waves;
// stage 2: one output channel per wave, std folded in via fast rcp.

constexpr int NTRIP = 69;
constexpr int NL    = 6;
constexpr int BATCH = 1024;
constexpr int ROW   = 288;     // complex elements per activation/output row
constexpr int MID_LDS = 4224;  // float2 slots for mid buffer
constexpr int MAXIT = 64;

struct Meta {
    int tl1[NTRIP], tl2[NTRIP], tll[NTRIP];
    int tf1[NTRIP], tf2[NTRIP];
    int ttloc[NTRIP];
    int trip_of_l[NL][16];
    int ntrips[NL];
    int mid_tau[NL], std_off[NL], w_off[NL], f_l[NL];
    int nch[NL];
    int ch_start[NL][4], ch_cnt[NL][4];
    int nit[NL];
    int it_slot[NL][MAXIT], it_m0[NL][MAXIT], it_m1[NL][MAXIT];
    int it_wave[NL][MAXIT], it_ch[NL][MAXIT];
};

constexpr int win_lo(int l1, int l2, int l, int mi) {
    int v = mi - l + l1 - l2; return v < 0 ? 0 : v;
}
constexpr int win_hi(int l1, int l2, int l, int mi) {
    int v = mi - l + l1 + l2; return v > 2 * l1 ? 2 * l1 : v;
}

constexpr Meta build_meta() {
    Meta m{};
    int fl[NL] = {};
    {
        int acc = 0;
        for (int l = 0; l < NL; l++) { fl[l] = acc; m.f_l[l] = acc; acc += 8 * (2 * l + 1); }
    }
    int idx = 0;
    for (int l1 = 0; l1 <= 5; l1++)
        for (int l2 = 0; l2 <= l1; l2++) {
            int lmax = (l1 + l2 < 5) ? (l1 + l2) : 5;
            for (int l = l1 - l2; l <= lmax; l++) {
                m.tl1[idx] = l1; m.tl2[idx] = l2; m.tll[idx] = l;
                m.tf1[idx] = fl[l1]; m.tf2[idx] = fl[l2];
                m.ttloc[idx] = 64 * m.ntrips[l];
                m.trip_of_l[l][m.ntrips[l]] = idx;
                m.ntrips[l]++;
                idx++;
            }
        }
    int so = 0, wo = 0;
    for (int l = 0; l < NL; l++) {
        m.mid_tau[l] = 64 * m.ntrips[l];
        m.std_off[l] = so; so += m.mid_tau[l];
        m.w_off[l]   = wo; wo += 8 * m.mid_tau[l];
    }
    for (int l = 0; l < NL; l++) {
        const int TW = 2 * l + 1;
        const int maxslot = MID_LDS / (64 * TW);
        const int ntl = m.ntrips[l];
        const int nch = (ntl + maxslot - 1) / maxslot;
        m.nch[l] = nch;
        int done = 0;
        for (int c = 0; c < nch; c++) {
            int cnt = (ntl - done + (nch - c) - 1) / (nch - c);
            m.ch_start[l][c] = done; m.ch_cnt[l][c] = cnt; done += cnt;
        }
        // build items: split slots into <=4 cost-equalized m-ranges
        int nit = 0;
        for (int c = 0; c < nch; c++) {
            const int it_first = nit;
            for (int si = m.ch_start[l][c]; si < m.ch_start[l][c] + m.ch_cnt[l][c]; si++) {
                int trip = m.trip_of_l[l][si];
                int l1 = m.tl1[trip], l2 = m.tl2[trip];
                int wm[16] = {}; int tot = 0;
                for (int mi = 0; mi < TW; mi++) {
                    wm[mi] = win_hi(l1, l2, l, mi) - win_lo(l1, l2, l, mi) + 1;
                    tot += wm[mi];
                }
                int np = tot <= 18 ? 1 : (tot + 17) / 18;
                if (np > 4) np = 4;
                if (np > TW) np = TW;
                int mcur = 0, acc2 = 0;
                for (int p = 0; p < np; p++) {
                    int target = (tot * (p + 1)) / np;
                    int m0 = mcur;
                    while (mcur < TW - (np - 1 - p) && (acc2 < target || mcur == m0)) {
                        acc2 += wm[mcur]; mcur++;
                    }
                    m.it_slot[l][nit] = si;
                    m.it_m0[l][nit] = m0;
                    m.it_m1[l][nit] = mcur - 1;
                    m.it_ch[l][nit] = c;
                    nit++;
                }
            }
            // greedy cost-balanced assignment of this chunk's items to 8 waves
            int cost[MAXIT] = {}; bool asg[MAXIT] = {};
            for (int i = it_first; i < nit; i++) {
                int trip = m.trip_of_l[l][m.it_slot[l][i]];
                int l1 = m.tl1[trip], l2 = m.tl2[trip];
                int tc = 0;
                for (int mi = m.it_m0[l][i]; mi <= m.it_m1[l][i]; mi++)
                    tc += win_hi(l1, l2, l, mi) - win_lo(l1, l2, l, mi) + 1;
                cost[i] = tc * 6 + (2 * l1 + 2 * l2 + 2) * 2;
            }
            int load[8] = {};
            for (int k = it_first; k < nit; k++) {
                int best = -1, bc = -1;
                for (int i = it_first; i < nit; i++)
                    if (!asg[i] && cost[i] > bc) { bc = cost[i]; best = i; }
                asg[best] = true;
                int wsel = 0;
                for (int w2 = 1; w2 < 8; w2++) if (load[w2] < load[wsel]) wsel = w2;
                m.it_wave[l][best] = wsel;
                load[wsel] += bc;
            }
        }
        m.nit[l] = nit;
    }
    return m;
}

constexpr Meta MT = build_meta();
constexpr int WLEN = 35328;
static_assert(MT.w_off[5] + 8 * MT.mid_tau[5] == WLEN, "wlen");
static_assert(MT.std_off[5] + MT.mid_tau[5] == 4416, "stdlen");

// ---------------------------------------------------- constexpr CG coeffs ---
constexpr double cfact(int n) {
    double r = 1.0;
    for (int i = 2; i <= n; i++) r *= (double)i;
    return r;
}
constexpr double csqrt(double x) {
    double g = x > 1.0 ? x : 1.0;
    for (int i = 0; i < 100; i++) g = 0.5 * (g + x / g);
    return g;
}
constexpr float cg_coeff(int l1, int l2, int l, int m1, int m2, int m) {
    if (m1 + m2 != m) return 0.0f;
    double pre = csqrt((double)(2 * l + 1) * cfact(l + l1 - l2) * cfact(l - l1 + l2) *
                       cfact(l1 + l2 - l) / cfact(l1 + l2 + l + 1));
    pre *= csqrt(cfact(l + m) * cfact(l - m) * cfact(l1 - m1) * cfact(l1 + m1) *
                 cfact(l2 - m2) * cfact(l2 + m2));
    double s = 0.0;
    for (int k = 0; k <= l1 + l2 - l; k++) {
        int d0 = k, d1 = l1 + l2 - l - k, d2 = l1 - m1 - k;
        int d3 = l2 + m2 - k, d4 = l - l2 + m1 + k, d5 = l - l1 - m2 + k;
        if (d0 < 0 || d1 < 0 || d2 < 0 || d3 < 0 || d4 < 0 || d5 < 0) continue;
        double den = cfact(d0) * cfact(d1) * cfact(d2) * cfact(d3) * cfact(d4) * cfact(d5);
        s += ((k & 1) ? -1.0 : 1.0) / den;
    }
    return (float)(pre * s);
}

// helpers for per-item F row subranges (constexpr)
constexpr int rng_alo(int l1, int l2, int l, int m0, int m1) {
    int r = 2 * l1;
    for (int mi = m0; mi <= m1; mi++) { int v = win_lo(l1, l2, l, mi); if (v < r) r = v; }
    return r;
}
constexpr int rng_ahi(int l1, int l2, int l, int m0, int m1) {
    int r = 0;
    for (int mi = m0; mi <= m1; mi++) { int v = win_hi(l1, l2, l, mi); if (v > r) r = v; }
    return r;
}
constexpr int rng_clo(int l1, int l2, int l, int m0, int m1) {
    int r = 2 * l2;
    for (int mi = m0; mi <= m1; mi++) {
        int v = (mi - l) + l1 + l2 - win_hi(l1, l2, l, mi); if (v < r) r = v;
    }
    return r;
}
constexpr int rng_chi(int l1, int l2, int l, int m0, int m1) {
    int r = 0;
    for (int mi = m0; mi <= m1; mi++) {
        int v = (mi - l) + l1 + l2 - win_lo(l1, l2, l, mi); if (v > r) r = v;
    }
    return r;
}

// compile-time for
template <int... Is, class F>
__device__ __forceinline__ void static_for_impl(std::integer_sequence<int, Is...>, F&& f) {
    (f(std::integral_constant<int, Is>{}), ...);
}
template <int N, class F>
__device__ __forceinline__ void static_for(F&& f) {
    static_for_impl(std::make_integer_sequence<int, N>{}, (F&&)f);
}

// ------------------------------------------------------------- main kernel --
template <int L>
__device__ __forceinline__ void process_l(int b, int tid,
                                          const float2* __restrict__ F,
                                          float2* __restrict__ mid,
                                          const float2* __restrict__ wts,
                                          const float* __restrict__ stdv,
                                          float2* __restrict__ out) {
    constexpr int TW  = 2 * L + 1;
    constexpr int NCH = MT.nch[L];
    constexpr int NT  = MT.mid_tau[L];

    const int wid  = tid >> 6;     // wave 0..7 (= output channel in stage 2)
    const int lane = tid & 63;
    const int t = lane >> 3, s = lane & 7;

    float2 acc[TW];
#pragma unroll
    for (int i = 0; i < TW; i++) acc[i] = make_float2(0.f, 0.f);

    static_for<NCH>([&](auto CHc) {
        constexpr int CH  = decltype(CHc)::value;
        constexpr int S0  = MT.ch_start[L][CH];
        constexpr int CNT = MT.ch_cnt[L][CH];
        constexpr int CT  = CNT * 64;
        static_assert(CT * TW <= MID_LDS, "chunk fits");

        __syncthreads();   // previous consumers of `mid` done (covers F load too)

        // ---- stage 1: mid[m][T] via balanced (slot, m-range) items -------
        static_for<MT.nit[L]>([&](auto ITc) {
            constexpr int IT = decltype(ITc)::value;
            if constexpr (MT.it_ch[L][IT] == CH) {
                constexpr int SI   = MT.it_slot[L][IT];
                constexpr int TRIP = MT.trip_of_l[L][SI];
                constexpr int L1   = MT.tl1[TRIP];
                constexpr int L2v  = MT.tl2[TRIP];
                constexpr int N1   = 2 * L1 + 1, N2 = 2 * L2v + 1;
                constexpr int M0   = MT.it_m0[L][IT], M1 = MT.it_m1[L][IT];
                constexpr int ALO  = rng_alo(L1, L2v, L, M0, M1);
                constexpr int AHI  = rng_ahi(L1, L2v, L, M0, M1);
                constexpr int CLO  = rng_clo(L1, L2v, L, M0, M1);
                constexpr int CHI_ = rng_chi(L1, L2v, L, M0, M1);
                if (MT.it_wave[L][IT] == wid) {
                    const float2* F1 = F + MT.tf1[TRIP] + t * N1;
                    const float2* F2 = F + MT.tf2[TRIP] + s * N2;
                    float2 f1[AHI - ALO + 1], f2[CHI_ - CLO + 1];
#pragma unroll
                    for (int i = 0; i <= AHI - ALO; i++) f1[i] = F1[ALO + i];
#pragma unroll
                    for (int i = 0; i <= CHI_ - CLO; i++) f2[i] = F2[CLO + i];
                    const int Tloc = (MT.ttloc[TRIP] - S0 * 64) + lane;
                    static_for<M1 - M0 + 1>([&](auto MIc) {
                        constexpr int MI   = M0 + decltype(MIc)::value;
                        constexpr int BASE = MI - L;
                        constexpr int LO   = win_lo(L1, L2v, L, MI);
                        constexpr int HI   = win_hi(L1, L2v, L, MI);
                        float re = 0.f, im = 0.f;
                        static_for<HI - LO + 1>([&](auto Kc) {
                            constexpr int AI = LO + decltype(Kc)::value;
                            constexpr int CI = BASE + L1 + L2v - AI;
                            constexpr float cv = cg_coeff(L1, L2v, L, AI - L1, CI - L2v, BASE);
                            if constexpr (cv != 0.0f) {
                                const float2 a = f1[AI - ALO], c2 = f2[CI - CLO];
                                re = fmaf(cv, fmaf(-a.y, c2.y, a.x * c2.x), re);
                                im = fmaf(cv, fmaf(a.y, c2.x, a.x * c2.y), im);
                            }
                        });
                        mid[MI * CT + Tloc] = make_float2(re, im);
                    });
                }
            }
        });
        __syncthreads();

        // ---- stage 2: acc[m] += sum_T (W[o,T]/std[T]) * mid[m][T], o=wid --
        const float2* Wb = wts + MT.w_off[L] + wid * NT + S0 * 64;
        const float*  Sb = stdv + MT.std_off[L] + S0 * 64;
        constexpr int NP4 = CNT / 2;
#pragma unroll
        for (int p = 0; p < NP4; p++) {
            const int T = p * 128 + lane * 2;
            const float4 wr = *reinterpret_cast<const float4*>(Wb + T);
            const float2 sd = *reinterpret_cast<const float2*>(Sb + T);
            const float i0 = __builtin_amdgcn_rcpf(sd.x + 1e-5f);
            const float i1 = __builtin_amdgcn_rcpf(sd.y + 1e-5f);
            const float wx0 = wr.x * i0, wy0 = wr.y * i0;
            const float wx1 = wr.z * i1, wy1 = wr.w * i1;
#pragma unroll
            for (int mi = 0; mi < TW; mi++) {
                const float4 mv = *reinterpret_cast<const float4*>(mid + mi * CT + T);
                acc[mi].x = fmaf(wx0, mv.x, fmaf(-wy0, mv.y,
                             fmaf(wx1, mv.z, fmaf(-wy1, mv.w, acc[mi].x))));
                acc[mi].y = fmaf(wx0, mv.y, fmaf(wy0, mv.x,
                             fmaf(wx1, mv.w, fmaf(wy1, mv.z, acc[mi].y))));
            }
        }
        if constexpr (CNT & 1) {
            const int T = (CNT - 1) * 64 + lane;
            const float2 wr = Wb[T];
            const float inv = __builtin_amdgcn_rcpf(Sb[T] + 1e-5f);
            const float wx = wr.x * inv, wy = wr.y * inv;
#pragma unroll
            for (int mi = 0; mi < TW; mi++) {
                const float2 mv = mid[mi * CT + T];
                acc[mi].x = fmaf(wx, mv.x, fmaf(-wy, mv.y, acc[mi].x));
                acc[mi].y = fmaf(wx, mv.y, fmaf(wy, mv.x, acc[mi].y));
            }
        }
    });

    // full-wave reduction; lane 0 writes o = wid
#pragma unroll
    for (int mi = 0; mi < TW; mi++) {
        float rx = acc[mi].x, ry = acc[mi].y;
#pragma unroll
        for (int off = 32; off >= 1; off >>= 1) {
            rx += __shfl_xor(rx, off, 64);
            ry += __shfl_xor(ry, off, 64);
        }
        acc[mi] = make_float2(rx, ry);
    }
    if (lane == 0) {
        float2* orow = out + (size_t)b * ROW + MT.f_l[L] + wid * TW;
#pragma unroll
        for (int mi = 0; mi < TW; mi++) orow[mi] = acc[mi];
    }
}

__global__ __launch_bounds__(512, 8) void fup_main(const float2* __restrict__ act,
                                                   const float2* __restrict__ wts,
                                                   const float* __restrict__ stdv,
                                                   float2* __restrict__ out) {
    __shared__ float2 F[ROW];
    __shared__ __align__(16) float2 mid[MID_LDS];
    const int b = blockIdx.x;
    const int tid = threadIdx.x;
    const float2* arow = act + (size_t)b * ROW;
    if (tid < ROW) F[tid] = arow[tid];
    // sync happens at top of first chunk inside process_l<0>
    process_l<0>(b, tid, F, mid, wts, stdv, out);
    process_l<1>(b, tid, F, mid, wts, stdv, out);
    process_l<2>(b, tid, F, mid, wts, stdv, out);
    process_l<3>(b, tid, F, mid, wts, stdv, out);
    process_l<4>(b, tid, F, mid, wts, stdv, out);
    process_l<5>(b, tid, F, mid, wts, stdv, out);
}

// ----------------------------------------------------------------- launch ---
extern "C" void kernel_launch(void* const* d_in, const int* in_sizes, int n_in,
                              void* d_out, int out_size, void* d_ws, size_t ws_size,
                              hipStream_t stream) {
    const float2* act  = (const float2*)d_in[0];
    const float2* wts  = (const float2*)d_in[1];
    const float*  stdv = (const float*)d_in[2];
    float2* out = (float2*)d_out;

    hipLaunchKernelGGL(fup_main, dim3(BATCH), dim3(512), 0, stream,
                       act, wts, stdv, out);
}

// Round 7
// 119.840 us; speedup vs baseline: 6.3299x; 6.3299x over previous
//
#include <hip/hip_runtime.h>
#include <hip/hip_bf16.h>
#include <utility>

// fUpModule CG tensor product, MAXL=5, TAUS=OUT_TAUS=8, BATCH=1024, fp32 I/O.
// R7 (= R6 fixed): single kernel. 256 threads, launch_bounds(256,4) (VGPR cap
// 128 -- R5's spill came from capping at 64). Occupancy raised via LDS: mid
// shrunk to 2880 float2 -> ~25 KB/block -> 6 blocks/CU (24 waves/CU).
// l=3/4/5 now need 3 chunks each -> ch arrays sized [4] (R6's compile bug).
// Stage 1: whole slots for l<=2, cost-split m-ranges for l>=3, greedy over
// 4 waves. Stage 2: 2 output channels per wave (4x mid re-read), std folded
// in with v_rcp_f32.

constexpr int NTRIP = 69;
constexpr int NL    = 6;
constexpr int BATCH = 1024;
constexpr int ROW   = 288;     // complex elements per activation/output row
constexpr int MID_LDS = 2880;  // float2 slots for mid buffer (22.5 KB)
constexpr int MAXIT = 64;
constexpr int MAXCH = 4;

struct Meta {
    int tl1[NTRIP], tl2[NTRIP], tll[NTRIP];
    int tf1[NTRIP], tf2[NTRIP];
    int ttloc[NTRIP];
    int trip_of_l[NL][16];
    int ntrips[NL];
    int mid_tau[NL], std_off[NL], w_off[NL], f_l[NL];
    int nch[NL];
    int ch_start[NL][MAXCH], ch_cnt[NL][MAXCH];
    int nit[NL];
    int it_slot[NL][MAXIT], it_m0[NL][MAXIT], it_m1[NL][MAXIT];
    int it_wave[NL][MAXIT], it_ch[NL][MAXIT];
};

constexpr int win_lo(int l1, int l2, int l, int mi) {
    int v = mi - l + l1 - l2; return v < 0 ? 0 : v;
}
constexpr int win_hi(int l1, int l2, int l, int mi) {
    int v = mi - l + l1 + l2; return v > 2 * l1 ? 2 * l1 : v;
}

constexpr Meta build_meta() {
    Meta m{};
    int fl[NL] = {};
    {
        int acc = 0;
        for (int l = 0; l < NL; l++) { fl[l] = acc; m.f_l[l] = acc; acc += 8 * (2 * l + 1); }
    }
    int idx = 0;
    for (int l1 = 0; l1 <= 5; l1++)
        for (int l2 = 0; l2 <= l1; l2++) {
            int lmax = (l1 + l2 < 5) ? (l1 + l2) : 5;
            for (int l = l1 - l2; l <= lmax; l++) {
                m.tl1[idx] = l1; m.tl2[idx] = l2; m.tll[idx] = l;
                m.tf1[idx] = fl[l1]; m.tf2[idx] = fl[l2];
                m.ttloc[idx] = 64 * m.ntrips[l];
                m.trip_of_l[l][m.ntrips[l]] = idx;
                m.ntrips[l]++;
                idx++;
            }
        }
    int so = 0, wo = 0;
    for (int l = 0; l < NL; l++) {
        m.mid_tau[l] = 64 * m.ntrips[l];
        m.std_off[l] = so; so += m.mid_tau[l];
        m.w_off[l]   = wo; wo += 8 * m.mid_tau[l];
    }
    for (int l = 0; l < NL; l++) {
        const int TW = 2 * l + 1;
        const int maxslot = MID_LDS / (64 * TW);
        const int ntl = m.ntrips[l];
        const int nch = (ntl + maxslot - 1) / maxslot;
        m.nch[l] = nch;
        if (nch > MAXCH) return Meta{};   // poison -> static_asserts fire
        int done = 0;
        for (int c = 0; c < nch; c++) {
            int cnt = (ntl - done + (nch - c) - 1) / (nch - c);
            m.ch_start[l][c] = done; m.ch_cnt[l][c] = cnt; done += cnt;
        }
        // items: l<=2 whole slots; l=3,4 split into 2 m-ranges; l=5 into 4
        const int npmax = (l <= 2) ? 1 : (l <= 4 ? 2 : 4);
        int nit = 0;
        for (int c = 0; c < nch; c++) {
            const int it_first = nit;
            for (int si = m.ch_start[l][c]; si < m.ch_start[l][c] + m.ch_cnt[l][c]; si++) {
                int trip = m.trip_of_l[l][si];
                int l1 = m.tl1[trip], l2 = m.tl2[trip];
                int wm[16] = {}; int tot = 0;
                for (int mi = 0; mi < TW; mi++) {
                    wm[mi] = win_hi(l1, l2, l, mi) - win_lo(l1, l2, l, mi) + 1;
                    tot += wm[mi];
                }
                int np = npmax;
                if (np > TW) np = TW;
                int mcur = 0, acc2 = 0;
                for (int p = 0; p < np; p++) {
                    int target = (tot * (p + 1)) / np;
                    int m0 = mcur;
                    while (mcur < TW - (np - 1 - p) && (acc2 < target || mcur == m0)) {
                        acc2 += wm[mcur]; mcur++;
                    }
                    if (nit >= MAXIT) return Meta{};
                    m.it_slot[l][nit] = si;
                    m.it_m0[l][nit] = m0;
                    m.it_m1[l][nit] = mcur - 1;
                    m.it_ch[l][nit] = c;
                    nit++;
                }
            }
            // greedy cost-balanced assignment of this chunk's items to 4 waves
            int cost[MAXIT] = {}; bool asg[MAXIT] = {};
            for (int i = it_first; i < nit; i++) {
                int trip = m.trip_of_l[l][m.it_slot[l][i]];
                int l1 = m.tl1[trip], l2 = m.tl2[trip];
                int tc = 0;
                for (int mi = m.it_m0[l][i]; mi <= m.it_m1[l][i]; mi++)
                    tc += win_hi(l1, l2, l, mi) - win_lo(l1, l2, l, mi) + 1;
                cost[i] = tc * 6 + (2 * l1 + 2 * l2 + 2) * 2;
            }
            int load[4] = {};
            for (int k = it_first; k < nit; k++) {
                int best = -1, bc = -1;
                for (int i = it_first; i < nit; i++)
                    if (!asg[i] && cost[i] > bc) { bc = cost[i]; best = i; }
                asg[best] = true;
                int wsel = 0;
                for (int w2 = 1; w2 < 4; w2++) if (load[w2] < load[wsel]) wsel = w2;
                m.it_wave[l][best] = wsel;
                load[wsel] += bc;
            }
        }
        m.nit[l] = nit;
    }
    return m;
}

constexpr Meta MT = build_meta();
constexpr int WLEN = 35328;
static_assert(MT.w_off[5] + 8 * MT.mid_tau[5] == WLEN, "wlen (meta poisoned?)");
static_assert(MT.std_off[5] + MT.mid_tau[5] == 4416, "stdlen");
static_assert(MT.nch[3] <= MAXCH && MT.nch[4] <= MAXCH && MT.nch[5] <= MAXCH, "nch");

// ---------------------------------------------------- constexpr CG coeffs ---
constexpr double cfact(int n) {
    double r = 1.0;
    for (int i = 2; i <= n; i++) r *= (double)i;
    return r;
}
constexpr double csqrt(double x) {
    double g = x > 1.0 ? x : 1.0;
    for (int i = 0; i < 100; i++) g = 0.5 * (g + x / g);
    return g;
}
constexpr float cg_coeff(int l1, int l2, int l, int m1, int m2, int m) {
    if (m1 + m2 != m) return 0.0f;
    double pre = csqrt((double)(2 * l + 1) * cfact(l + l1 - l2) * cfact(l - l1 + l2) *
                       cfact(l1 + l2 - l) / cfact(l1 + l2 + l + 1));
    pre *= csqrt(cfact(l + m) * cfact(l - m) * cfact(l1 - m1) * cfact(l1 + m1) *
                 cfact(l2 - m2) * cfact(l2 + m2));
    double s = 0.0;
    for (int k = 0; k <= l1 + l2 - l; k++) {
        int d0 = k, d1 = l1 + l2 - l - k, d2 = l1 - m1 - k;
        int d3 = l2 + m2 - k, d4 = l - l2 + m1 + k, d5 = l - l1 - m2 + k;
        if (d0 < 0 || d1 < 0 || d2 < 0 || d3 < 0 || d4 < 0 || d5 < 0) continue;
        double den = cfact(d0) * cfact(d1) * cfact(d2) * cfact(d3) * cfact(d4) * cfact(d5);
        s += ((k & 1) ? -1.0 : 1.0) / den;
    }
    return (float)(pre * s);
}

// per-item F row subranges (constexpr)
constexpr int rng_alo(int l1, int l2, int l, int m0, int m1) {
    int r = 2 * l1;
    for (int mi = m0; mi <= m1; mi++) { int v = win_lo(l1, l2, l, mi); if (v < r) r = v; }
    return r;
}
constexpr int rng_ahi(int l1, int l2, int l, int m0, int m1) {
    int r = 0;
    for (int mi = m0; mi <= m1; mi++) { int v = win_hi(l1, l2, l, mi); if (v > r) r = v; }
    return r;
}
constexpr int rng_clo(int l1, int l2, int l, int m0, int m1) {
    int r = 2 * l2;
    for (int mi = m0; mi <= m1; mi++) {
        int v = (mi - l) + l1 + l2 - win_hi(l1, l2, l, mi); if (v < r) r = v;
    }
    return r;
}
constexpr int rng_chi(int l1, int l2, int l, int m0, int m1) {
    int r = 0;
    for (int mi = m0; mi <= m1; mi++) {
        int v = (mi - l) + l1 + l2 - win_lo(l1, l2, l, mi); if (v > r) r = v;
    }
    return r;
}

// compile-time for
template <int... Is, class F>
__device__ __forceinline__ void static_for_impl(std::integer_sequence<int, Is...>, F&& f) {
    (f(std::integral_constant<int, Is>{}), ...);
}
template <int N, class F>
__device__ __forceinline__ void static_for(F&& f) {
    static_for_impl(std::make_integer_sequence<int, N>{}, (F&&)f);
}

// ------------------------------------------------------------- main kernel --
template <int L>
__device__ __forceinline__ void process_l(int b, int tid,
                                          const float2* __restrict__ F,
                                          float2* __restrict__ mid,
                                          const float2* __restrict__ wts,
                                          const float* __restrict__ stdv,
                                          float2* __restrict__ out) {
    constexpr int TW  = 2 * L + 1;
    constexpr int NCH = MT.nch[L];
    constexpr int NT  = MT.mid_tau[L];

    const int wid  = tid >> 6;     // wave 0..3
    const int lane = tid & 63;
    const int t = lane >> 3, s = lane & 7;

    float2 acc0[TW], acc1[TW];     // o = wid, o = wid + 4
#pragma unroll
    for (int i = 0; i < TW; i++) { acc0[i] = make_float2(0.f, 0.f); acc1[i] = make_float2(0.f, 0.f); }

    static_for<NCH>([&](auto CHc) {
        constexpr int CH  = decltype(CHc)::value;
        constexpr int S0  = MT.ch_start[L][CH];
        constexpr int CNT = MT.ch_cnt[L][CH];
        constexpr int CT  = CNT * 64;
        static_assert(CT * TW <= MID_LDS, "chunk fits");

        __syncthreads();   // previous consumers of `mid` done (covers F load too)

        // ---- stage 1: mid[m][T] via balanced (slot, m-range) items -------
        static_for<MT.nit[L]>([&](auto ITc) {
            constexpr int IT = decltype(ITc)::value;
            if constexpr (MT.it_ch[L][IT] == CH) {
                constexpr int SI   = MT.it_slot[L][IT];
                constexpr int TRIP = MT.trip_of_l[L][SI];
                constexpr int L1   = MT.tl1[TRIP];
                constexpr int L2v  = MT.tl2[TRIP];
                constexpr int N1   = 2 * L1 + 1, N2 = 2 * L2v + 1;
                constexpr int M0   = MT.it_m0[L][IT], M1 = MT.it_m1[L][IT];
                constexpr int ALO  = rng_alo(L1, L2v, L, M0, M1);
                constexpr int AHI  = rng_ahi(L1, L2v, L, M0, M1);
                constexpr int CLO  = rng_clo(L1, L2v, L, M0, M1);
                constexpr int CHI_ = rng_chi(L1, L2v, L, M0, M1);
                if (MT.it_wave[L][IT] == wid) {
                    const float2* F1 = F + MT.tf1[TRIP] + t * N1;
                    const float2* F2 = F + MT.tf2[TRIP] + s * N2;
                    float2 f1[AHI - ALO + 1], f2[CHI_ - CLO + 1];
#pragma unroll
                    for (int i = 0; i <= AHI - ALO; i++) f1[i] = F1[ALO + i];
#pragma unroll
                    for (int i = 0; i <= CHI_ - CLO; i++) f2[i] = F2[CLO + i];
                    const int Tloc = (MT.ttloc[TRIP] - S0 * 64) + lane;
                    static_for<M1 - M0 + 1>([&](auto MIc) {
                        constexpr int MI   = M0 + decltype(MIc)::value;
                        constexpr int BASE = MI - L;
                        constexpr int LO   = win_lo(L1, L2v, L, MI);
                        constexpr int HI   = win_hi(L1, L2v, L, MI);
                        float re = 0.f, im = 0.f;
                        static_for<HI - LO + 1>([&](auto Kc) {
                            constexpr int AI = LO + decltype(Kc)::value;
                            constexpr int CI = BASE + L1 + L2v - AI;
                            constexpr float cv = cg_coeff(L1, L2v, L, AI - L1, CI - L2v, BASE);
                            if constexpr (cv != 0.0f) {
                                const float2 a = f1[AI - ALO], c2 = f2[CI - CLO];
                                re = fmaf(cv, fmaf(-a.y, c2.y, a.x * c2.x), re);
                                im = fmaf(cv, fmaf(a.y, c2.x, a.x * c2.y), im);
                            }
                        });
                        mid[MI * CT + Tloc] = make_float2(re, im);
                    });
                }
            }
        });
        __syncthreads();

        // ---- stage 2: acc[o,m] += sum_T (W[o,T]/std[T])*mid[m][T] --------
        const float2* W0 = wts + MT.w_off[L] + wid * NT + S0 * 64;
        const float2* W1 = wts + MT.w_off[L] + (wid + 4) * NT + S0 * 64;
        const float*  Sb = stdv + MT.std_off[L] + S0 * 64;
        for (int T = lane * 2; T < CT; T += 128) {
            const float4 w0r = *reinterpret_cast<const float4*>(W0 + T);
            const float4 w1r = *reinterpret_cast<const float4*>(W1 + T);
            const float2 sd  = *reinterpret_cast<const float2*>(Sb + T);
            const float i0 = __builtin_amdgcn_rcpf(sd.x + 1e-5f);
            const float i1 = __builtin_amdgcn_rcpf(sd.y + 1e-5f);
            const float4 w0 = make_float4(w0r.x * i0, w0r.y * i0, w0r.z * i1, w0r.w * i1);
            const float4 w1 = make_float4(w1r.x * i0, w1r.y * i0, w1r.z * i1, w1r.w * i1);
#pragma unroll
            for (int mi = 0; mi < TW; mi++) {
                const float4 mv = *reinterpret_cast<const float4*>(mid + mi * CT + T);
                acc0[mi].x = fmaf(w0.x, mv.x, fmaf(-w0.y, mv.y,
                              fmaf(w0.z, mv.z, fmaf(-w0.w, mv.w, acc0[mi].x))));
                acc0[mi].y = fmaf(w0.x, mv.y, fmaf(w0.y, mv.x,
                              fmaf(w0.z, mv.w, fmaf(w0.w, mv.z, acc0[mi].y))));
                acc1[mi].x = fmaf(w1.x, mv.x, fmaf(-w1.y, mv.y,
                              fmaf(w1.z, mv.z, fmaf(-w1.w, mv.w, acc1[mi].x))));
                acc1[mi].y = fmaf(w1.x, mv.y, fmaf(w1.y, mv.x,
                              fmaf(w1.z, mv.w, fmaf(w1.w, mv.z, acc1[mi].y))));
            }
        }
    });

    // merge-reduce: lo half ends with sum for o=wid, hi half for o=wid+4
    const bool lo = (lane < 32);
    float2 red[TW];
#pragma unroll
    for (int mi = 0; mi < TW; mi++) {
        float gx = lo ? acc1[mi].x : acc0[mi].x;   // value to give away
        float gy = lo ? acc1[mi].y : acc0[mi].y;
        float rx = (lo ? acc0[mi].x : acc1[mi].x) + __shfl_xor(gx, 32, 64);
        float ry = (lo ? acc0[mi].y : acc1[mi].y) + __shfl_xor(gy, 32, 64);
#pragma unroll
        for (int off = 16; off >= 1; off >>= 1) {
            rx += __shfl_xor(rx, off, 64);
            ry += __shfl_xor(ry, off, 64);
        }
        red[mi] = make_float2(rx, ry);
    }
    if (lane == 0 || lane == 32) {
        const int o = wid + (lo ? 0 : 4);
        float2* orow = out + (size_t)b * ROW + MT.f_l[L] + o * TW;
#pragma unroll
        for (int mi = 0; mi < TW; mi++) orow[mi] = red[mi];
    }
}

__global__ __launch_bounds__(256, 4) void fup_main(const float2* __restrict__ act,
                                                   const float2* __restrict__ wts,
                                                   const float* __restrict__ stdv,
                                                   float2* __restrict__ out) {
    __shared__ float2 F[ROW];
    __shared__ __align__(16) float2 mid[MID_LDS];
    const int b = blockIdx.x;
    const int tid = threadIdx.x;
    const float2* arow = act + (size_t)b * ROW;
    for (int i = tid; i < ROW; i += 256) F[i] = arow[i];
    // sync happens at top of first chunk inside process_l<0>
    process_l<0>(b, tid, F, mid, wts, stdv, out);
    process_l<1>(b, tid, F, mid, wts, stdv, out);
    process_l<2>(b, tid, F, mid, wts, stdv, out);
    process_l<3>(b, tid, F, mid, wts, stdv, out);
    process_l<4>(b, tid, F, mid, wts, stdv, out);
    process_l<5>(b, tid, F, mid, wts, stdv, out);
}

// ----------------------------------------------------------------- launch ---
extern "C" void kernel_launch(void* const* d_in, const int* in_sizes, int n_in,
                              void* d_out, int out_size, void* d_ws, size_t ws_size,
                              hipStream_t stream) {
    const float2* act  = (const float2*)d_in[0];
    const float2* wts  = (const float2*)d_in[1];
    const float*  stdv = (const float*)d_in[2];
    float2* out = (float2*)d_out;

    hipLaunchKernelGGL(fup_main, dim3(BATCH), dim3(256), 0, stream,
                       act, wts, stdv, out);
}